// Round 6
// baseline (1261.912 us; speedup 1.0000x reference)
//
#include <hip/hip_runtime.h>
#include <hip/hip_bf16.h>

typedef __hip_bfloat16 bf16;
typedef __attribute__((ext_vector_type(8))) short short8;
typedef __attribute__((ext_vector_type(4))) short short4v;
typedef __attribute__((ext_vector_type(4))) float floatx4;

__device__ __forceinline__ floatx4 mfma16(short8 a, short8 b, floatx4 c) {
  return __builtin_amdgcn_mfma_f32_16x16x32_bf16(a, b, c, 0, 0, 0);
}

__device__ __forceinline__ float wave_sum(float v) {
#pragma unroll
  for (int off = 1; off < 64; off <<= 1) v += __shfl_xor(v, off);
  return v;
}

// swizzled LDS fragment read: row stride 384B, XOR bits[6:4] with row&7
__device__ __forceinline__ short8 lds_frag(const char* base, int row, int kb) {
  return *(const short8*)(base + row * 384 + (kb ^ ((row & 7) << 4)));
}
// same, row stride 128B
__device__ __forceinline__ short8 lds_frag128(const char* base, int row, int kb) {
  return *(const short8*)(base + row * 128 + (kb ^ ((row & 7) << 4)));
}

// ---------------------------------------------------------------------------
// Weight transpose + bf16 cast: w (K x N) fp32 -> wt (N x K) bf16
// ---------------------------------------------------------------------------
__global__ __launch_bounds__(256) void k_wt(const float* __restrict__ w,
                                            bf16* __restrict__ wt, int K, int N) {
  int id = blockIdx.x * 256 + threadIdx.x;
  if (id < K * N) {
    int n = id / K;
    int k = id - n * K;
    wt[id] = __float2bfloat16(w[(long)k * N + n]);
  }
}

// ---------------------------------------------------------------------------
// LayerNorm over C=192. One wave per row. GATHER=true applies cyclic shift
// (-3,-3) + window partition: output row order = (b, wi, wj, ti, tj).
// ---------------------------------------------------------------------------
template <bool GATHER>
__global__ __launch_bounds__(256) void k_ln(const float* __restrict__ xin,
                                            const float* __restrict__ w,
                                            const float* __restrict__ b,
                                            bf16* __restrict__ out) {
  const int lane = threadIdx.x & 63;
  const long row = (long)blockIdx.x * 4 + (threadIdx.x >> 6);
  long srow;
  if (GATHER) {
    int win = (int)(row / 49);
    int token = (int)(row - (long)win * 49);
    int bimg = win >> 6, wi = (win & 63) >> 3, wj = win & 7;
    int ti = token / 7, tj = token - ti * 7;
    int h = wi * 7 + ti + 3; if (h >= 56) h -= 56;
    int ww = wj * 7 + tj + 3; if (ww >= 56) ww -= 56;
    srow = (long)bimg * 3136 + h * 56 + ww;
  } else {
    srow = row;
  }
  const float* src = xin + srow * 192;
  float v0 = src[lane], v1 = src[lane + 64], v2 = src[lane + 128];
  float mu = wave_sum(v0 + v1 + v2) * (1.f / 192.f);
  float d0 = v0 - mu, d1 = v1 - mu, d2 = v2 - mu;
  float var = wave_sum(d0 * d0 + d1 * d1 + d2 * d2) * (1.f / 192.f);
  float rs = rsqrtf(var + 1e-5f);
  bf16* dst = out + row * 192;
  dst[lane]       = __float2bfloat16(d0 * rs * w[lane] + b[lane]);
  dst[lane + 64]  = __float2bfloat16(d1 * rs * w[lane + 64] + b[lane + 64]);
  dst[lane + 128] = __float2bfloat16(d2 * rs * w[lane + 128] + b[lane + 128]);
}

// ---------------------------------------------------------------------------
// Fused windowed attention: one block per window (4096 blocks, 256 threads).
// Per block: stage x-window -> per head {QKV GEMM from global weights,
// S=QK^T, softmax(+rel-bias+shift-mask), PV} -> proj GEMM + residual +
// window-reverse scatter to fp32 out. No qkv/att intermediates in HBM.
// Wave w owns token rows [w*16, w*16+16) throughout.
// LDS: As 24.6K + Os 24.6K + Qs 5.1K + Ks 5.1K + Vt 4.6K + Ps 9.2K = 73.2 KB
//  -> 2 blocks/CU.
// ---------------------------------------------------------------------------
__global__ __launch_bounds__(256, 2) void k_swin(const bf16* __restrict__ xw,
                                                 const bf16* __restrict__ wq,
                                                 const float* __restrict__ qkvb,
                                                 const float* __restrict__ rpb,
                                                 const bf16* __restrict__ wp,
                                                 const float* __restrict__ projb,
                                                 const float* __restrict__ xres,
                                                 float* __restrict__ outf) {
  __shared__ __align__(16) char As[64 * 384];   // x window, swizzled
  __shared__ __align__(16) char Os[64 * 384];   // attn out (concat heads)
  __shared__ __align__(16) bf16 Qs[64 * 40];
  __shared__ __align__(16) bf16 Ks[64 * 40];
  __shared__ __align__(16) bf16 Vt[32 * 72];    // [d][token]
  __shared__ __align__(16) bf16 Ps[64 * 72];
  const int t = threadIdx.x, lane = t & 63, wid = t >> 6;
  const int lanelo = lane & 15, quad = lane >> 4;
  const int w = blockIdx.x;
  const long rowbase = (long)w * 49;
  const int wm = wid * 16;  // this wave's token band

  // ---- stage x window (49 rows, zero-pad to 64), swizzled ----
  {
    const char* src = (const char*)(xw + rowbase * 192);
#pragma unroll
    for (int i = 0; i < 6; i++) {
      int c = i * 256 + t;
      int r = c / 24, j = c - r * 24;
      uint4 v;
      if (r < 49) v = *(const uint4*)(src + (long)r * 384 + j * 16);
      else { v.x = 0u; v.y = 0u; v.z = 0u; v.w = 0u; }
      *(uint4*)(As + r * 384 + ((j * 16) ^ ((r & 7) << 4))) = v;
    }
  }

  // ---- head-independent softmax tables ----
  const int w_in = w & 63, wiw = w_in >> 3, wjw = w_in & 7;
  int cTi[4], cTj[4], cLab[4];
  bool cval[4];
#pragma unroll
  for (int ni = 0; ni < 4; ni++) {
    int j = ni * 16 + lanelo;
    cval[ni] = (j < 49);
    if (j > 48) j = 48;
    int ti = j / 7, tj = j - ti * 7;
    int rr = wiw * 7 + ti, cc = wjw * 7 + tj;
    cTi[ni] = ti; cTj[ni] = tj;
    cLab[ni] = ((rr < 49) ? 0 : (rr < 53 ? 1 : 2)) * 3 +
               ((cc < 49) ? 0 : (cc < 53 ? 1 : 2));
  }
  int ridx6[4][4];     // rpb row index * 6
  float msub[4][4];    // 100 if masked else 0
#pragma unroll
  for (int reg = 0; reg < 4; reg++) {
    int i = wm + quad * 4 + reg;
    if (i > 48) i = 48;
    int ti = i / 7, tj = i - ti * 7;
    int rr = wiw * 7 + ti, cc = wjw * 7 + tj;
    int rlab = ((rr < 49) ? 0 : (rr < 53 ? 1 : 2)) * 3 +
               ((cc < 49) ? 0 : (cc < 53 ? 1 : 2));
#pragma unroll
    for (int ni = 0; ni < 4; ni++) {
      ridx6[reg][ni] = ((ti - cTi[ni] + 6) * 13 + (tj - cTj[ni] + 6)) * 6;
      msub[reg][ni] = (rlab != cLab[ni]) ? 100.f : 0.f;
    }
  }
  __syncthreads();  // As ready

  const float scale = 0.17677669529663687f;  // 1/sqrt(32)

  for (int h = 0; h < 6; h++) {
    // ---- QKV GEMM for head h: rows [wm,wm+16), cols {Qd,Kd,Vd} (96) ----
    floatx4 aq[6];
#pragma unroll
    for (int ni = 0; ni < 6; ni++) aq[ni] = (floatx4){0.f, 0.f, 0.f, 0.f};
#pragma unroll
    for (int kk = 0; kk < 6; kk++) {
      const int kb = kk * 64 + quad * 16;
      short8 af = lds_frag(As, wm + lanelo, kb);
#pragma unroll
      for (int ni = 0; ni < 6; ni++) {
        const int wrow = (ni >> 1) * 192 + h * 32 + (ni & 1) * 16 + lanelo;
        short8 bf = *(const short8*)((const char*)wq + (long)wrow * 384 + kb);
        aq[ni] = mfma16(af, bf, aq[ni]);
      }
    }
    __syncthreads();  // previous head's readers done -> safe to overwrite

    // epilogue: Q,K row-major [token][d]; V transposed [d][token]
#pragma unroll
    for (int ni = 0; ni < 6; ni++) {
      const int p = ni >> 1;
      const int d = (ni & 1) * 16 + lanelo;
      const float bb = qkvb[p * 192 + h * 32 + d];
      if (p < 2) {
        bf16* dst = (p == 0) ? Qs : Ks;
#pragma unroll
        for (int reg = 0; reg < 4; reg++) {
          int tok = wm + quad * 4 + reg;
          dst[tok * 40 + d] = __float2bfloat16(aq[ni][reg] + bb);
        }
      } else {
        union { short4v s; bf16 hh[4]; } pv;
#pragma unroll
        for (int reg = 0; reg < 4; reg++)
          pv.hh[reg] = __float2bfloat16(aq[ni][reg] + bb);
        *(short4v*)(&Vt[d * 72 + wm + quad * 4]) = pv.s;
      }
    }
    __syncthreads();  // Q/K/Vt for head h visible

    // ---- S = Q K^T for this wave's 16 rows ----
    short8 aqf = *(const short8*)(&Qs[(wm + lanelo) * 40 + quad * 8]);
    floatx4 aS[4];
#pragma unroll
    for (int ni = 0; ni < 4; ni++) {
      short8 bk = *(const short8*)(&Ks[(ni * 16 + lanelo) * 40 + quad * 8]);
      aS[ni] = mfma16(aqf, bk, (floatx4){0.f, 0.f, 0.f, 0.f});
    }

    // ---- softmax (rel-pos bias + shift mask), per output row ----
    float rinv[4];
#pragma unroll
    for (int reg = 0; reg < 4; reg++) {
      float sv[4];
      float mx = -1e30f;
#pragma unroll
      for (int ni = 0; ni < 4; ni++) {
        float s;
        if (cval[ni]) {
          s = aS[ni][reg] * scale + rpb[ridx6[reg][ni] + h] - msub[reg][ni];
        } else {
          s = -1e30f;
        }
        sv[ni] = s;
        mx = fmaxf(mx, s);
      }
      mx = fmaxf(mx, __shfl_xor(mx, 1));
      mx = fmaxf(mx, __shfl_xor(mx, 2));
      mx = fmaxf(mx, __shfl_xor(mx, 4));
      mx = fmaxf(mx, __shfl_xor(mx, 8));
      float sum = 0.f;
#pragma unroll
      for (int ni = 0; ni < 4; ni++) {
        float p = __expf(sv[ni] - mx);
        sv[ni] = p;
        sum += p;
      }
      sum += __shfl_xor(sum, 1);
      sum += __shfl_xor(sum, 2);
      sum += __shfl_xor(sum, 4);
      sum += __shfl_xor(sum, 8);
      rinv[reg] = 1.f / sum;
#pragma unroll
      for (int ni = 0; ni < 4; ni++) aS[ni][reg] = sv[ni];
    }

    // P -> LDS (wave-local rows; same-wave RAW handled by lgkmcnt)
#pragma unroll
    for (int ni = 0; ni < 4; ni++)
#pragma unroll
      for (int reg = 0; reg < 4; reg++)
        Ps[(wm + quad * 4 + reg) * 72 + ni * 16 + lanelo] =
            __float2bfloat16(aS[ni][reg]);

    // ---- O = P * V : 16 rows x 32 cols, K=64 ----
    floatx4 aO[2];
    aO[0] = (floatx4){0.f, 0.f, 0.f, 0.f};
    aO[1] = (floatx4){0.f, 0.f, 0.f, 0.f};
#pragma unroll
    for (int ks = 0; ks < 2; ks++) {
      short8 ap = *(const short8*)(&Ps[(wm + lanelo) * 72 + ks * 32 + quad * 8]);
#pragma unroll
      for (int ni = 0; ni < 2; ni++) {
        short8 bv = *(const short8*)(&Vt[(ni * 16 + lanelo) * 72 + ks * 32 + quad * 8]);
        aO[ni] = mfma16(ap, bv, aO[ni]);
      }
    }
    // write O band (cols h*32..h*32+31), swizzled for proj read
#pragma unroll
    for (int ni = 0; ni < 2; ni++)
#pragma unroll
      for (int reg = 0; reg < 4; reg++) {
        int tok = wm + quad * 4 + reg;
        int cb = 2 * (h * 32 + ni * 16 + lanelo);
        *(bf16*)(Os + tok * 384 + (cb ^ ((tok & 7) << 4))) =
            __float2bfloat16(aO[ni][reg] * rinv[reg]);
      }
  }  // heads
  __syncthreads();  // Os complete (defensive; Os rows are wave-local)

  // ---- proj: out 16x192 per wave, K=192, + bias + residual + scatter ----
  floatx4 accp[12];
#pragma unroll
  for (int ni = 0; ni < 12; ni++) accp[ni] = (floatx4){0.f, 0.f, 0.f, 0.f};
#pragma unroll
  for (int kk = 0; kk < 6; kk++) {
    const int kb = kk * 64 + quad * 16;
    short8 af = lds_frag(Os, wm + lanelo, kb);
#pragma unroll
    for (int ni = 0; ni < 12; ni++) {
      short8 bf = *(const short8*)((const char*)wp +
                                   (long)(ni * 16 + lanelo) * 384 + kb);
      accp[ni] = mfma16(af, bf, accp[ni]);
    }
  }
#pragma unroll
  for (int reg = 0; reg < 4; reg++) {
    const int tok = wm + quad * 4 + reg;
    if (tok < 49) {
      int ti = tok / 7, tj = tok - ti * 7;
      int hh = wiw * 7 + ti + 3; if (hh >= 56) hh -= 56;
      int ww2 = wjw * 7 + tj + 3; if (ww2 >= 56) ww2 -= 56;
      const long orow = (long)(w >> 6) * 3136 + hh * 56 + ww2;
#pragma unroll
      for (int ni = 0; ni < 12; ni++) {
        const int c = ni * 16 + lanelo;
        outf[orow * 192 + c] = accp[ni][reg] + projb[c] + xres[orow * 192 + c];
      }
    }
  }
}

// ---------------------------------------------------------------------------
// Fused LN2 + fc1 + GELU + fc2 + residual, in-place on the fp32 tensor.
// 64 rows/block, 256 threads, 3136 blocks, 4 blocks/CU (LDS 40KB).
// Direct-global weight fragments; Hs double-buffered; 1 barrier/chunk.
// ---------------------------------------------------------------------------
__global__ __launch_bounds__(256, 4) void k_mlp(float* xres,
                                                const float* __restrict__ lw,
                                                const float* __restrict__ lb,
                                                const bf16* __restrict__ w1t,
                                                const float* __restrict__ b1,
                                                const bf16* __restrict__ w2t,
                                                const float* __restrict__ b2) {
  __shared__ __align__(16) char As[64 * 384];     // LN'd rows, K=192 (swizzled)
  __shared__ __align__(16) char Hs[2][64 * 128];  // gelu(hid) chunk dbuf
  const int t = threadIdx.x, lane = t & 63, wid = t >> 6;
  const int lanelo = lane & 15, quad = lane >> 4;
  const long row0 = (long)blockIdx.x * 64;

  // ---- LN2 -> As (bf16, row-XOR swizzled); 16 rows per wave ----
  for (int i = 0; i < 16; i++) {
    int r = wid * 16 + i;
    const float* src = xres + (row0 + r) * 192;
    float v0 = src[lane], v1 = src[lane + 64], v2 = src[lane + 128];
    float mu = wave_sum(v0 + v1 + v2) * (1.f / 192.f);
    float d0 = v0 - mu, d1 = v1 - mu, d2 = v2 - mu;
    float var = wave_sum(d0 * d0 + d1 * d1 + d2 * d2) * (1.f / 192.f);
    float rs = rsqrtf(var + 1e-5f);
    int sw = (r & 7) << 4;
    *(bf16*)(As + r * 384 + ((2 * lane) ^ sw)) =
        __float2bfloat16(d0 * rs * lw[lane] + lb[lane]);
    *(bf16*)(As + r * 384 + ((128 + 2 * lane) ^ sw)) =
        __float2bfloat16(d1 * rs * lw[lane + 64] + lb[lane + 64]);
    *(bf16*)(As + r * 384 + ((256 + 2 * lane) ^ sw)) =
        __float2bfloat16(d2 * rs * lw[lane + 128] + lb[lane + 128]);
  }

  floatx4 acc2[4][3];
#pragma unroll
  for (int mi = 0; mi < 4; mi++)
#pragma unroll
    for (int ni = 0; ni < 3; ni++) acc2[mi][ni] = (floatx4){0.f, 0.f, 0.f, 0.f};

  __syncthreads();  // As ready

  const int hcol = wid * 16 + lanelo;          // GEMM1 col owned by this lane
  const int ocol0 = wid * 48;                  // GEMM2 col base for this wave

  for (int nc = 0; nc < 12; nc++) {
    // GEMM1: hid chunk cols [nc*64 + wid*16, +16), 64 rows, K=192.
    const char* w1p = (const char*)w1t + (long)(nc * 64 + hcol) * 384;
    floatx4 acc1[4];
#pragma unroll
    for (int mi = 0; mi < 4; mi++) acc1[mi] = (floatx4){0.f, 0.f, 0.f, 0.f};
#pragma unroll
    for (int kk = 0; kk < 6; kk++) {
      const int kb = kk * 64 + quad * 16;
      short8 bf = *(const short8*)(w1p + kb);
#pragma unroll
      for (int mi = 0; mi < 4; mi++) {
        short8 af = lds_frag(As, mi * 16 + lanelo, kb);
        acc1[mi] = mfma16(af, bf, acc1[mi]);
      }
    }

    // bias + exact GELU -> Hs[nc&1] (bf16, swizzled)
    char* H = Hs[nc & 1];
    const float b1v = b1[nc * 64 + hcol];
#pragma unroll
    for (int mi = 0; mi < 4; mi++)
#pragma unroll
      for (int reg = 0; reg < 4; reg++) {
        int r = mi * 16 + quad * 4 + reg;
        float v = acc1[mi][reg] + b1v;
        v = 0.5f * v * (1.f + erff(v * 0.70710678118654752f));
        *(bf16*)(H + r * 128 + ((2 * hcol) ^ ((r & 7) << 4))) =
            __float2bfloat16(v);
      }
    __syncthreads();  // Hs[nc&1] ready; also guards WAR on Hs[(nc-1)&1]

    // GEMM2 partial: out 64x192 += H(64x64) * W2chunk^T, wave tile 64x48.
#pragma unroll
    for (int ks = 0; ks < 2; ks++) {
      const int kb = ks * 64 + quad * 16;
      short8 ha[4];
#pragma unroll
      for (int mi = 0; mi < 4; mi++)
        ha[mi] = lds_frag128(H, mi * 16 + lanelo, kb);
#pragma unroll
      for (int ni = 0; ni < 3; ni++) {
        short8 bv = *(const short8*)((const char*)w2t +
                                     (long)(ocol0 + ni * 16 + lanelo) * 1536 +
                                     nc * 128 + kb);
#pragma unroll
        for (int mi = 0; mi < 4; mi++)
          acc2[mi][ni] = mfma16(ha[mi], bv, acc2[mi][ni]);
      }
    }
  }

  // epilogue: + bias2 + residual, fp32 in-place
#pragma unroll
  for (int mi = 0; mi < 4; mi++)
#pragma unroll
    for (int ni = 0; ni < 3; ni++) {
      const int c = ocol0 + ni * 16 + lanelo;
      const float b2v = b2[c];
#pragma unroll
      for (int reg = 0; reg < 4; reg++) {
        const long g = (row0 + mi * 16 + quad * 4 + reg) * 192 + c;
        xres[g] = acc2[mi][ni][reg] + b2v + xres[g];
      }
    }
}

// ---------------------------------------------------------------------------
extern "C" void kernel_launch(void* const* d_in, const int* in_sizes, int n_in,
                              void* d_out, int out_size, void* d_ws, size_t ws_size,
                              hipStream_t stream) {
  const float* x     = (const float*)d_in[0];
  const float* n1w   = (const float*)d_in[1];
  const float* n1b   = (const float*)d_in[2];
  const float* qkvw  = (const float*)d_in[3];
  const float* qkvb  = (const float*)d_in[4];
  const float* rpb   = (const float*)d_in[5];
  const float* projw = (const float*)d_in[6];
  const float* projb = (const float*)d_in[7];
  const float* n2w   = (const float*)d_in[8];
  const float* n2b   = (const float*)d_in[9];
  const float* fc1w  = (const float*)d_in[10];
  const float* fc1b  = (const float*)d_in[11];
  const float* fc2w  = (const float*)d_in[12];
  const float* fc2b  = (const float*)d_in[13];
  float* outf = (float*)d_out;  // residual buffer, then final output

  // workspace layout:
  //   B0 [0,        77070336)  xw bf16 (200704x192)
  //   W  [154140672, ...)      bf16 weights (~0.9 MB)
  char* ws = (char*)d_ws;
  bf16* xw      = (bf16*)(ws + 0);
  bf16* wt_qkv  = (bf16*)(ws + 154140672LL);                  // 576x192
  bf16* wt_proj = (bf16*)(ws + 154140672LL + 221184LL);       // 192x192
  bf16* wt_fc1  = (bf16*)(ws + 154140672LL + 294912LL);       // 768x192
  bf16* wt_fc2  = (bf16*)(ws + 154140672LL + 589824LL);       // 192x768

  // transpose + cast weights to bf16 (N x K)
  k_wt<<<dim3((192 * 576 + 255) / 256), 256, 0, stream>>>(qkvw, wt_qkv, 192, 576);
  k_wt<<<dim3((192 * 192 + 255) / 256), 256, 0, stream>>>(projw, wt_proj, 192, 192);
  k_wt<<<dim3((192 * 768 + 255) / 256), 256, 0, stream>>>(fc1w, wt_fc1, 192, 768);
  k_wt<<<dim3((768 * 192 + 255) / 256), 256, 0, stream>>>(fc2w, wt_fc2, 768, 192);

  // LN1 + shift + window partition -> xw (window-order rows, full tensor)
  k_ln<true><<<dim3(50176), 256, 0, stream>>>(x, n1w, n1b, xw);

  // fused attention: qkv + windowed MHA + proj + residual, one block/window
  k_swin<<<dim3(4096), 256, 0, stream>>>(xw, wt_qkv, qkvb, rpb, wt_proj, projb,
                                         x, outf);

  // fused LN2 + MLP + residual, in-place on d_out (64 rows per block)
  k_mlp<<<dim3(3136), 256, 0, stream>>>(outf, n2w, n2b, wt_fc1, fc1b,
                                        wt_fc2, fc2b);
}

// Round 8
// 995.551 us; speedup vs baseline: 1.2676x; 1.2676x over previous
//
#include <hip/hip_runtime.h>
#include <hip/hip_bf16.h>

typedef __hip_bfloat16 bf16;
typedef __attribute__((ext_vector_type(8))) short short8;
typedef __attribute__((ext_vector_type(4))) short short4v;
typedef __attribute__((ext_vector_type(4))) float floatx4;

__device__ __forceinline__ floatx4 mfma16(short8 a, short8 b, floatx4 c) {
  return __builtin_amdgcn_mfma_f32_16x16x32_bf16(a, b, c, 0, 0, 0);
}

__device__ __forceinline__ float wave_sum(float v) {
#pragma unroll
  for (int off = 1; off < 64; off <<= 1) v += __shfl_xor(v, off);
  return v;
}

// swizzled LDS fragment read: row stride 384B, XOR bits[6:4] with row&7
__device__ __forceinline__ short8 lds_frag(const char* base, int row, int kb) {
  return *(const short8*)(base + row * 384 + (kb ^ ((row & 7) << 4)));
}
// same, row stride 128B
__device__ __forceinline__ short8 lds_frag128(const char* base, int row, int kb) {
  return *(const short8*)(base + row * 128 + (kb ^ ((row & 7) << 4)));
}

// ---------------------------------------------------------------------------
// Weight transpose + bf16 cast: w (K x N) fp32 -> wt (N x K) bf16
// ---------------------------------------------------------------------------
__global__ __launch_bounds__(256) void k_wt(const float* __restrict__ w,
                                            bf16* __restrict__ wt, int K, int N) {
  int id = blockIdx.x * 256 + threadIdx.x;
  if (id < K * N) {
    int n = id / K;
    int k = id - n * K;
    wt[id] = __float2bfloat16(w[(long)k * N + n]);
  }
}

// ---------------------------------------------------------------------------
// LayerNorm over C=192. One wave per row. GATHER=true applies cyclic shift
// (-3,-3) + window partition: output row order = (b, wi, wj, ti, tj).
// ---------------------------------------------------------------------------
template <bool GATHER>
__global__ __launch_bounds__(256) void k_ln(const float* __restrict__ xin,
                                            const float* __restrict__ w,
                                            const float* __restrict__ b,
                                            bf16* __restrict__ out) {
  const int lane = threadIdx.x & 63;
  const long row = (long)blockIdx.x * 4 + (threadIdx.x >> 6);
  long srow;
  if (GATHER) {
    int win = (int)(row / 49);
    int token = (int)(row - (long)win * 49);
    int bimg = win >> 6, wi = (win & 63) >> 3, wj = win & 7;
    int ti = token / 7, tj = token - ti * 7;
    int h = wi * 7 + ti + 3; if (h >= 56) h -= 56;
    int ww = wj * 7 + tj + 3; if (ww >= 56) ww -= 56;
    srow = (long)bimg * 3136 + h * 56 + ww;
  } else {
    srow = row;
  }
  const float* src = xin + srow * 192;
  float v0 = src[lane], v1 = src[lane + 64], v2 = src[lane + 128];
  float mu = wave_sum(v0 + v1 + v2) * (1.f / 192.f);
  float d0 = v0 - mu, d1 = v1 - mu, d2 = v2 - mu;
  float var = wave_sum(d0 * d0 + d1 * d1 + d2 * d2) * (1.f / 192.f);
  float rs = rsqrtf(var + 1e-5f);
  bf16* dst = out + row * 192;
  dst[lane]       = __float2bfloat16(d0 * rs * w[lane] + b[lane]);
  dst[lane + 64]  = __float2bfloat16(d1 * rs * w[lane + 64] + b[lane + 64]);
  dst[lane + 128] = __float2bfloat16(d2 * rs * w[lane + 128] + b[lane + 128]);
}

// ---------------------------------------------------------------------------
// Fused windowed attention v2: one block per window, 384 threads (6 waves),
// HEAD-PER-WAVE. Wave h computes head h for all 64 (padded) tokens with
// wave-PRIVATE Q/K/V LDS -> only 3 barriers per block:
//   stage As -> B1 -> {QKV gemm, S, softmax, PV} (independent) -> B2 ->
//   O->Os (As space reused) -> B3 -> proj + residual + scatter.
// LDS: As/Os 24.6K + 6 x (QK/P 10.25K + Vt 4.6K) = 113.7 KB -> 1 block/CU.
// ---------------------------------------------------------------------------
__global__ __launch_bounds__(384, 1) void k_swin(const bf16* __restrict__ xw,
                                                 const bf16* __restrict__ wq,
                                                 const float* __restrict__ qkvb,
                                                 const float* __restrict__ rpb,
                                                 const bf16* __restrict__ wp,
                                                 const float* __restrict__ projb,
                                                 const float* __restrict__ xres,
                                                 float* __restrict__ outf) {
  __shared__ __align__(16) char As[64 * 384];      // x window; later Os
  __shared__ __align__(16) bf16 QKP[6][5120];      // per wave: Q[0,2560) K[2560,5120); P overlays
  __shared__ __align__(16) bf16 Vts[6][32 * 72];   // per wave: [d][token]
  const int t = threadIdx.x, lane = t & 63, wid = t >> 6;  // wid == head
  const int lanelo = lane & 15, quad = lane >> 4;
  const int w = blockIdx.x;
  const long rowbase = (long)w * 49;
  bf16* Qs = QKP[wid];
  bf16* Ks = Qs + 2560;
  bf16* Ps = Qs;                 // overlays Q/K after S is consumed
  bf16* Vt = Vts[wid];

  // ---- stage x window (49 rows, zero-pad to 64), swizzled ----
  {
    const char* src = (const char*)(xw + rowbase * 192);
#pragma unroll
    for (int i = 0; i < 4; i++) {
      int c = i * 384 + t;
      int r = c / 24, j = c - r * 24;
      uint4 v;
      if (r < 49) v = *(const uint4*)(src + (long)r * 384 + j * 16);
      else { v.x = 0u; v.y = 0u; v.z = 0u; v.w = 0u; }
      *(uint4*)(As + r * 384 + ((j * 16) ^ ((r & 7) << 4))) = v;
    }
  }

  // ---- per-lane key-column tables (head-independent) ----
  const int w_in = w & 63, wiw = w_in >> 3, wjw = w_in & 7;
  int cTi[4], cTj[4], cLab[4];
  bool cval[4];
#pragma unroll
  for (int ni = 0; ni < 4; ni++) {
    int j = ni * 16 + lanelo;
    cval[ni] = (j < 49);
    if (j > 48) j = 48;
    int ti = j / 7, tj = j - ti * 7;
    int rr = wiw * 7 + ti, cc = wjw * 7 + tj;
    cTi[ni] = ti; cTj[ni] = tj;
    cLab[ni] = ((rr < 49) ? 0 : (rr < 53 ? 1 : 2)) * 3 +
               ((cc < 49) ? 0 : (cc < 53 ? 1 : 2));
  }
  __syncthreads();  // B1: As ready

  const float scale = 0.17677669529663687f;  // 1/sqrt(32)

  // ---- QKV GEMM for head wid: all 64 rows x 96 cols (Q|K|V), K=192 ----
  {
    floatx4 aq[4][6];
#pragma unroll
    for (int mi = 0; mi < 4; mi++)
#pragma unroll
      for (int ni = 0; ni < 6; ni++) aq[mi][ni] = (floatx4){0.f, 0.f, 0.f, 0.f};
#pragma unroll
    for (int kk = 0; kk < 6; kk++) {
      const int kb = kk * 64 + quad * 16;
      short8 af[4];
#pragma unroll
      for (int mi = 0; mi < 4; mi++) af[mi] = lds_frag(As, mi * 16 + lanelo, kb);
#pragma unroll
      for (int ni = 0; ni < 6; ni++) {
        const int wrow = (ni >> 1) * 192 + wid * 32 + (ni & 1) * 16 + lanelo;
        short8 bf = *(const short8*)((const char*)wq + (long)wrow * 384 + kb);
#pragma unroll
        for (int mi = 0; mi < 4; mi++) aq[mi][ni] = mfma16(af[mi], bf, aq[mi][ni]);
      }
    }
    // epilogue: Q,K row-major [token][d] stride 40; V transposed [d][token]
#pragma unroll
    for (int ni = 0; ni < 6; ni++) {
      const int p = ni >> 1;
      const int d = (ni & 1) * 16 + lanelo;
      const float bb = qkvb[p * 192 + wid * 32 + d];
      if (p < 2) {
        bf16* dst = (p == 0) ? Qs : Ks;
#pragma unroll
        for (int mi = 0; mi < 4; mi++)
#pragma unroll
          for (int reg = 0; reg < 4; reg++) {
            int tok = mi * 16 + quad * 4 + reg;
            dst[tok * 40 + d] = __float2bfloat16(aq[mi][ni][reg] + bb);
          }
      } else {
#pragma unroll
        for (int mi = 0; mi < 4; mi++) {
          union { short4v s; bf16 hh[4]; } pv;
#pragma unroll
          for (int reg = 0; reg < 4; reg++)
            pv.hh[reg] = __float2bfloat16(aq[mi][ni][reg] + bb);
          *(short4v*)(&Vt[d * 72 + mi * 16 + quad * 4]) = pv.s;
        }
      }
    }
  }
  // (wave-private LDS: in-wave DS ordering suffices, no barrier)

  // ---- S = Q K^T : 64x64, then softmax, then P -> LDS ----
  float rinv[16];
  {
    floatx4 aS[4][4];
#pragma unroll
    for (int mi = 0; mi < 4; mi++) {
      short8 aqf = *(const short8*)(&Qs[(mi * 16 + lanelo) * 40 + quad * 8]);
#pragma unroll
      for (int ni = 0; ni < 4; ni++) {
        short8 bk = *(const short8*)(&Ks[(ni * 16 + lanelo) * 40 + quad * 8]);
        aS[mi][ni] = mfma16(aqf, bk, (floatx4){0.f, 0.f, 0.f, 0.f});
      }
    }
#pragma unroll
    for (int mi = 0; mi < 4; mi++) {
#pragma unroll
      for (int reg = 0; reg < 4; reg++) {
        int i = mi * 16 + quad * 4 + reg;
        if (i > 48) i = 48;
        int ti = i / 7, tj = i - ti * 7;
        int rr = wiw * 7 + ti, cc = wjw * 7 + tj;
        int rlab = ((rr < 49) ? 0 : (rr < 53 ? 1 : 2)) * 3 +
                   ((cc < 49) ? 0 : (cc < 53 ? 1 : 2));
        float sv[4];
        float mx = -1e30f;
#pragma unroll
        for (int ni = 0; ni < 4; ni++) {
          float s;
          if (cval[ni]) {
            int ridx = (ti - cTi[ni] + 6) * 13 + (tj - cTj[ni] + 6);
            float bb = rpb[ridx * 6 + wid];
            if (rlab != cLab[ni]) bb -= 100.f;
            s = aS[mi][ni][reg] * scale + bb;
          } else {
            s = -1e30f;
          }
          sv[ni] = s;
          mx = fmaxf(mx, s);
        }
        mx = fmaxf(mx, __shfl_xor(mx, 1));
        mx = fmaxf(mx, __shfl_xor(mx, 2));
        mx = fmaxf(mx, __shfl_xor(mx, 4));
        mx = fmaxf(mx, __shfl_xor(mx, 8));
        float sum = 0.f;
#pragma unroll
        for (int ni = 0; ni < 4; ni++) {
          float p = __expf(sv[ni] - mx);
          sv[ni] = p;
          sum += p;
        }
        sum += __shfl_xor(sum, 1);
        sum += __shfl_xor(sum, 2);
        sum += __shfl_xor(sum, 4);
        sum += __shfl_xor(sum, 8);
        rinv[mi * 4 + reg] = 1.f / sum;
#pragma unroll
        for (int ni = 0; ni < 4; ni++) aS[mi][ni][reg] = sv[ni];
      }
    }
    // P -> LDS (overlays Q/K; same-wave DS ops are ordered)
#pragma unroll
    for (int mi = 0; mi < 4; mi++)
#pragma unroll
      for (int ni = 0; ni < 4; ni++)
#pragma unroll
        for (int reg = 0; reg < 4; reg++)
          Ps[(mi * 16 + quad * 4 + reg) * 72 + ni * 16 + lanelo] =
              __float2bfloat16(aS[mi][ni][reg]);
  }

  // ---- O = P * V : 64x32, K=64 ----
  floatx4 aO[4][2];
#pragma unroll
  for (int mi = 0; mi < 4; mi++)
#pragma unroll
    for (int ni = 0; ni < 2; ni++) aO[mi][ni] = (floatx4){0.f, 0.f, 0.f, 0.f};
#pragma unroll
  for (int ks = 0; ks < 2; ks++) {
#pragma unroll
    for (int mi = 0; mi < 4; mi++) {
      short8 ap = *(const short8*)(&Ps[(mi * 16 + lanelo) * 72 + ks * 32 + quad * 8]);
#pragma unroll
      for (int ni = 0; ni < 2; ni++) {
        short8 bv = *(const short8*)(&Vt[(ni * 16 + lanelo) * 72 + ks * 32 + quad * 8]);
        aO[mi][ni] = mfma16(ap, bv, aO[mi][ni]);
      }
    }
  }
  __syncthreads();  // B2: all waves done reading As (QKV) -> reuse as Os

  // ---- write O band (cols wid*32..+31) into Os (=As), swizzled ----
#pragma unroll
  for (int mi = 0; mi < 4; mi++)
#pragma unroll
    for (int ni = 0; ni < 2; ni++)
#pragma unroll
      for (int reg = 0; reg < 4; reg++) {
        int tok = mi * 16 + quad * 4 + reg;
        int cb = 2 * (wid * 32 + ni * 16 + lanelo);
        *(bf16*)(As + tok * 384 + (cb ^ ((tok & 7) << 4))) =
            __float2bfloat16(aO[mi][ni][reg] * rinv[mi * 4 + reg]);
      }
  __syncthreads();  // B3: Os complete

  // ---- proj: each wave does out cols [wid*32, +32), K=192 ----
  floatx4 accp[4][2];
#pragma unroll
  for (int mi = 0; mi < 4; mi++)
#pragma unroll
    for (int ni = 0; ni < 2; ni++) accp[mi][ni] = (floatx4){0.f, 0.f, 0.f, 0.f};
#pragma unroll
  for (int kk = 0; kk < 6; kk++) {
    const int kb = kk * 64 + quad * 16;
    short8 af[4];
#pragma unroll
    for (int mi = 0; mi < 4; mi++) af[mi] = lds_frag(As, mi * 16 + lanelo, kb);
#pragma unroll
    for (int ni = 0; ni < 2; ni++) {
      const int wrow = wid * 32 + ni * 16 + lanelo;
      short8 bf = *(const short8*)((const char*)wp + (long)wrow * 384 + kb);
#pragma unroll
      for (int mi = 0; mi < 4; mi++) accp[mi][ni] = mfma16(af[mi], bf, accp[mi][ni]);
    }
  }
  // epilogue: + bias + residual, window-reverse scatter (fp32)
#pragma unroll
  for (int mi = 0; mi < 4; mi++)
#pragma unroll
    for (int reg = 0; reg < 4; reg++) {
      const int tok = mi * 16 + quad * 4 + reg;
      if (tok < 49) {
        int ti = tok / 7, tj = tok - ti * 7;
        int hh = wiw * 7 + ti + 3; if (hh >= 56) hh -= 56;
        int ww2 = wjw * 7 + tj + 3; if (ww2 >= 56) ww2 -= 56;
        const long orow = (long)(w >> 6) * 3136 + hh * 56 + ww2;
#pragma unroll
        for (int ni = 0; ni < 2; ni++) {
          const int c = wid * 32 + ni * 16 + lanelo;
          outf[orow * 192 + c] = accp[mi][ni][reg] + projb[c] + xres[orow * 192 + c];
        }
      }
    }
}

// ---------------------------------------------------------------------------
// Fused LN2 + fc1 + GELU + fc2 + residual, in-place on the fp32 tensor.
// 64 rows/block, 256 threads, 3136 blocks, 4 blocks/CU (LDS 40KB).
// Direct-global weight fragments; Hs double-buffered; 1 barrier/chunk.
// ---------------------------------------------------------------------------
__global__ __launch_bounds__(256, 4) void k_mlp(float* xres,
                                                const float* __restrict__ lw,
                                                const float* __restrict__ lb,
                                                const bf16* __restrict__ w1t,
                                                const float* __restrict__ b1,
                                                const bf16* __restrict__ w2t,
                                                const float* __restrict__ b2) {
  __shared__ __align__(16) char As[64 * 384];     // LN'd rows, K=192 (swizzled)
  __shared__ __align__(16) char Hs[2][64 * 128];  // gelu(hid) chunk dbuf
  const int t = threadIdx.x, lane = t & 63, wid = t >> 6;
  const int lanelo = lane & 15, quad = lane >> 4;
  const long row0 = (long)blockIdx.x * 64;

  // ---- LN2 -> As (bf16, row-XOR swizzled); 16 rows per wave ----
  for (int i = 0; i < 16; i++) {
    int r = wid * 16 + i;
    const float* src = xres + (row0 + r) * 192;
    float v0 = src[lane], v1 = src[lane + 64], v2 = src[lane + 128];
    float mu = wave_sum(v0 + v1 + v2) * (1.f / 192.f);
    float d0 = v0 - mu, d1 = v1 - mu, d2 = v2 - mu;
    float var = wave_sum(d0 * d0 + d1 * d1 + d2 * d2) * (1.f / 192.f);
    float rs = rsqrtf(var + 1e-5f);
    int sw = (r & 7) << 4;
    *(bf16*)(As + r * 384 + ((2 * lane) ^ sw)) =
        __float2bfloat16(d0 * rs * lw[lane] + lb[lane]);
    *(bf16*)(As + r * 384 + ((128 + 2 * lane) ^ sw)) =
        __float2bfloat16(d1 * rs * lw[lane + 64] + lb[lane + 64]);
    *(bf16*)(As + r * 384 + ((256 + 2 * lane) ^ sw)) =
        __float2bfloat16(d2 * rs * lw[lane + 128] + lb[lane + 128]);
  }

  floatx4 acc2[4][3];
#pragma unroll
  for (int mi = 0; mi < 4; mi++)
#pragma unroll
    for (int ni = 0; ni < 3; ni++) acc2[mi][ni] = (floatx4){0.f, 0.f, 0.f, 0.f};

  __syncthreads();  // As ready

  const int hcol = wid * 16 + lanelo;          // GEMM1 col owned by this lane
  const int ocol0 = wid * 48;                  // GEMM2 col base for this wave

  for (int nc = 0; nc < 12; nc++) {
    // GEMM1: hid chunk cols [nc*64 + wid*16, +16), 64 rows, K=192.
    const char* w1p = (const char*)w1t + (long)(nc * 64 + hcol) * 384;
    floatx4 acc1[4];
#pragma unroll
    for (int mi = 0; mi < 4; mi++) acc1[mi] = (floatx4){0.f, 0.f, 0.f, 0.f};
#pragma unroll
    for (int kk = 0; kk < 6; kk++) {
      const int kb = kk * 64 + quad * 16;
      short8 bf = *(const short8*)(w1p + kb);
#pragma unroll
      for (int mi = 0; mi < 4; mi++) {
        short8 af = lds_frag(As, mi * 16 + lanelo, kb);
        acc1[mi] = mfma16(af, bf, acc1[mi]);
      }
    }

    // bias + exact GELU -> Hs[nc&1] (bf16, swizzled)
    char* H = Hs[nc & 1];
    const float b1v = b1[nc * 64 + hcol];
#pragma unroll
    for (int mi = 0; mi < 4; mi++)
#pragma unroll
      for (int reg = 0; reg < 4; reg++) {
        int r = mi * 16 + quad * 4 + reg;
        float v = acc1[mi][reg] + b1v;
        v = 0.5f * v * (1.f + erff(v * 0.70710678118654752f));
        *(bf16*)(H + r * 128 + ((2 * hcol) ^ ((r & 7) << 4))) =
            __float2bfloat16(v);
      }
    __syncthreads();  // Hs[nc&1] ready; also guards WAR on Hs[(nc-1)&1]

    // GEMM2 partial: out 64x192 += H(64x64) * W2chunk^T, wave tile 64x48.
#pragma unroll
    for (int ks = 0; ks < 2; ks++) {
      const int kb = ks * 64 + quad * 16;
      short8 ha[4];
#pragma unroll
      for (int mi = 0; mi < 4; mi++)
        ha[mi] = lds_frag128(H, mi * 16 + lanelo, kb);
#pragma unroll
      for (int ni = 0; ni < 3; ni++) {
        short8 bv = *(const short8*)((const char*)w2t +
                                     (long)(ocol0 + ni * 16 + lanelo) * 1536 +
                                     nc * 128 + kb);
#pragma unroll
        for (int mi = 0; mi < 4; mi++)
          acc2[mi][ni] = mfma16(ha[mi], bv, acc2[mi][ni]);
      }
    }
  }

  // epilogue: + bias2 + residual, fp32 in-place
#pragma unroll
  for (int mi = 0; mi < 4; mi++)
#pragma unroll
    for (int ni = 0; ni < 3; ni++) {
      const int c = ocol0 + ni * 16 + lanelo;
      const float b2v = b2[c];
#pragma unroll
      for (int reg = 0; reg < 4; reg++) {
        const long g = (row0 + mi * 16 + quad * 4 + reg) * 192 + c;
        xres[g] = acc2[mi][ni][reg] + b2v + xres[g];
      }
    }
}

// ---------------------------------------------------------------------------
extern "C" void kernel_launch(void* const* d_in, const int* in_sizes, int n_in,
                              void* d_out, int out_size, void* d_ws, size_t ws_size,
                              hipStream_t stream) {
  const float* x     = (const float*)d_in[0];
  const float* n1w   = (const float*)d_in[1];
  const float* n1b   = (const float*)d_in[2];
  const float* qkvw  = (const float*)d_in[3];
  const float* qkvb  = (const float*)d_in[4];
  const float* rpb   = (const float*)d_in[5];
  const float* projw = (const float*)d_in[6];
  const float* projb = (const float*)d_in[7];
  const float* n2w   = (const float*)d_in[8];
  const float* n2b   = (const float*)d_in[9];
  const float* fc1w  = (const float*)d_in[10];
  const float* fc1b  = (const float*)d_in[11];
  const float* fc2w  = (const float*)d_in[12];
  const float* fc2b  = (const float*)d_in[13];
  float* outf = (float*)d_out;  // residual buffer, then final output

  // workspace layout:
  //   B0 [0,        77070336)  xw bf16 (200704x192)
  //   W  [154140672, ...)      bf16 weights (~0.9 MB)
  char* ws = (char*)d_ws;
  bf16* xw      = (bf16*)(ws + 0);
  bf16* wt_qkv  = (bf16*)(ws + 154140672LL);                  // 576x192
  bf16* wt_proj = (bf16*)(ws + 154140672LL + 221184LL);       // 192x192
  bf16* wt_fc1  = (bf16*)(ws + 154140672LL + 294912LL);       // 768x192
  bf16* wt_fc2  = (bf16*)(ws + 154140672LL + 589824LL);       // 192x768

  // transpose + cast weights to bf16 (N x K)
  k_wt<<<dim3((192 * 576 + 255) / 256), 256, 0, stream>>>(qkvw, wt_qkv, 192, 576);
  k_wt<<<dim3((192 * 192 + 255) / 256), 256, 0, stream>>>(projw, wt_proj, 192, 192);
  k_wt<<<dim3((192 * 768 + 255) / 256), 256, 0, stream>>>(fc1w, wt_fc1, 192, 768);
  k_wt<<<dim3((768 * 192 + 255) / 256), 256, 0, stream>>>(fc2w, wt_fc2, 768, 192);

  // LN1 + shift + window partition -> xw (window-order rows, full tensor)
  k_ln<true><<<dim3(50176), 256, 0, stream>>>(x, n1w, n1b, xw);

  // fused attention: qkv + windowed MHA + proj + residual, one block/window
  k_swin<<<dim3(4096), 384, 0, stream>>>(xw, wt_qkv, qkvb, rpb, wt_proj, projb,
                                         x, outf);

  // fused LN2 + MLP + residual, in-place on d_out (64 rows per block)
  k_mlp<<<dim3(3136), 256, 0, stream>>>(outf, n2w, n2b, wt_fc1, fc1b,
                                        wt_fc2, fc2b);
}